// Round 8
// baseline (105.490 us; speedup 1.0000x reference)
//
#include <hip/hip_runtime.h>

#define T_LEN 256
#define NG 27              // 27 groups x 16 steps = 432 steps (max s needed = 430)

__device__ __forceinline__ float ex2(float x) { return __builtin_amdgcn_exp2f(x); }
__device__ __forceinline__ float rcp1p(float e) { return __builtin_amdgcn_rcpf(1.0f + e); }

// wave_shr:1 (0x138): lane i <- lane i-1 (lanes 0 keep old). VALU pipe.
__device__ __forceinline__ float dpp_wave_shr1(float v) {
    int i = __float_as_int(v);
    return __int_as_float(__builtin_amdgcn_update_dpp(i, i, 0x138, 0xF, 0xF, false));
}
// quad_perm [1,0,3,2] (ctrl 0xB1): swap adjacent lane pairs 0<->1, 2<->3. VALU pipe.
__device__ __forceinline__ float dpp_pair_swap(float v) {
    int i = __float_as_int(v);
    return __int_as_float(__builtin_amdgcn_update_dpp(i, i, 0xB1, 0xF, 0xF, false));
}

// FOUR waves (4 SIMDs), GATE-SPLIT lane pairs: global layer L = 32*wid + j is
// held by lanes 2j (r-gate) and 2j+1 (z-gate) of wave wid; both lanes carry an
// identical replica of h and the n-path. Schedule: cell (L,t) at step
// s = t + j + 48*wid (16-step skew per cross-wave seam).
//  - r/z sigmoid: ONE shared instruction stream with per-lane coefficients
//    (wi_rz, c_rz) -> per-wave transcendentals drop 6 -> 4, issue < chain.
//  - r<->z exchange: quad_perm pair swap (VALU, 2 cyc); both lanes then
//    redundantly compute n and h' -> replicas stay bitwise identical.
//  - layer handoff: double wave_shr:1 (lane 2j <- 2j-2, 2j+1 <- 2j-1): both
//    replica lanes receive layer j-1's (identical) h. Seam lanes 0,1 take the
//    group-prefetched feed instead.
//  - cross-wave seam (proven R7 scheme): every lane publishes h to its wave's
//    ring plane each step; consumer wave prefetches 16 broadcast reads of
//    slot (s-17), element 62 (layer j=31 replica) at group top; barrier per
//    16 steps bounds drift => written-before-barrier, overwrite at +64 safe.
//  - wave0 seam feed = x[s] via identical group-top broadcast reads of sx.
//  - validity gating off-chain: z := 1 when t invalid => h' == h exactly
//    (h starts 0; ring zero-inited; stale values never consumed).
__global__ __launch_bounds__(256, 1) void gru_stack_wavefront(
    const float* __restrict__ x,
    const float* __restrict__ w_ih,
    const float* __restrict__ w_hh,
    const float* __restrict__ b_ih,
    const float* __restrict__ b_hh,
    float* __restrict__ out)
{
    __shared__ float ring[4 * 64 * 64];   // [wid][slot][lane], 64 KiB
    __shared__ float sx[T_LEN];
    const int tid  = threadIdx.x;         // 0..255
    const int lane = tid & 63;
    const int wid  = tid >> 6;            // 0..3
    const int j    = lane >> 1;           // layer-within-wave 0..31
    const int p    = lane & 1;            // 0 = r-gate lane, 1 = z-gate lane
    const int L    = 32 * wid + j;        // global layer 0..127

    sx[tid & (T_LEN - 1)] = x[tid & (T_LEN - 1)];
    #pragma unroll
    for (int m = tid; m < 4 * 64 * 64; m += 256) ring[m] = 0.0f;

    const float L1 = -1.4426950408889634f;   // -log2(e)   (sigmoid scale)
    const float L2 = -2.8853900817779268f;   // -2*log2(e) (tanh scale)

    // gate-split r/z params (index p picks r or z; PyTorch gate order [r,z,n])
    const float wi_rz = L1 * w_ih[3 * L + p], wh_rz = L1 * w_hh[3 * L + p];
    const float b_rz  = L1 * (b_ih[3 * L + p] + b_hh[3 * L + p]);
    // n-path params (replicated on both lanes)
    const float wi_n = L2 * w_ih[3 * L + 2], bi_n = L2 * b_ih[3 * L + 2];
    const float wh_n = L2 * w_hh[3 * L + 2], bh_n = L2 * b_hh[3 * L + 2];

    float h = 0.0f;
    float c_rz = b_rz, g_n = bh_n;        // h-dependent precomputes (h=0)

    const int  toff   = j + 48 * wid;     // t = s - toff
    const bool seam   = (lane < 2);
    const bool w0     = (wid == 0);
    const bool isout  = (tid == 255);     // wave3 lane63: layer 127 (z replica)
    float pk[16];

    __syncthreads();                      // sx + ring init visible

    for (int g = 0; g < NG; ++g) {
        const int sb = 16 * g;

        // group-top prefetch of the seam feed (broadcast reads, off-chain)
        if (w0) {
            #pragma unroll
            for (int k = 0; k < 16; ++k)
                pk[k] = sx[(sb + k) & (T_LEN - 1)];          // x[s] (gated past 255)
        } else {
            const float* plane = &ring[(wid - 1) * 4096];
            #pragma unroll
            for (int k = 0; k < 16; ++k)
                pk[k] = plane[((sb + k - 17) & 63) * 64 + 62]; // h(32*wid-1, s-17 sched)
        }

        #pragma unroll
        for (int k = 0; k < 16; ++k) {
            const int s = sb + k;
            const bool valid = (unsigned)(s - toff) < (unsigned)T_LEN;

            // layer handoff: both replica lanes receive layer j-1's h
            float s1 = dpp_wave_shr1(h);
            float s2 = dpp_wave_shr1(s1);
            float in = seam ? pk[k] : s2;

            // shared r/z sigmoid stream (per-lane coefficients)
            float u   = fmaf(wi_rz, in, c_rz);
            float un0 = fmaf(wi_n,  in, bi_n);
            float rz  = rcp1p(ex2(u));            // r on even lanes, z on odd
            float other = dpp_pair_swap(rz);      // z on even, r on odd
            float rv = p ? other : rz;
            float zv = p ? rz : other;
            zv = valid ? zv : 1.0f;               // gate OFF the n-chain; z=1 => h'==h

            float un = fmaf(rv, g_n, un0);
            float n  = fmaf(2.0f, rcp1p(ex2(un)), -1.0f);
            h = fmaf(zv, h - n, n);               // (1-z)*n + z*h

            c_rz = fmaf(wh_rz, h, b_rz);          // off input-critical chain
            g_n  = fmaf(wh_n,  h, bh_n);

            ring[wid * 4096 + (s & 63) * 64 + lane] = h;   // publish (2-way alias: free)

            if (isout && valid) out[s - 175] = h;          // layer 127, t = s-175
        }
        __syncthreads();                                   // bounds wave drift (<16)
    }
}

extern "C" void kernel_launch(void* const* d_in, const int* in_sizes, int n_in,
                              void* d_out, int out_size, void* d_ws, size_t ws_size,
                              hipStream_t stream) {
    const float* x    = (const float*)d_in[0];  // [1,256]
    const float* w_ih = (const float*)d_in[1];  // [128,3,1]
    const float* w_hh = (const float*)d_in[2];  // [128,3,1]
    const float* b_ih = (const float*)d_in[3];  // [128,3]
    const float* b_hh = (const float*)d_in[4];  // [128,3]
    float* out = (float*)d_out;                 // [1,256]

    gru_stack_wavefront<<<1, 256, 0, stream>>>(x, w_ih, w_hh, b_ih, b_hh, out);
}